// Round 14
// baseline (1956.154 us; speedup 1.0000x reference)
//
#include <hip/hip_runtime.h>
#include <math.h>

#define BB 8
#define NN 2048
#define KNN 20
#define BN_INV 0.9999950000374997f

typedef __bf16 bf16x8 __attribute__((ext_vector_type(8)));
typedef __bf16 bf16x4 __attribute__((ext_vector_type(4)));
typedef float f32x4 __attribute__((ext_vector_type(4)));

// ---------------------------------------------------------------- unscramble
__global__ __launch_bounds__(256)
void k_unscramble(const float* __restrict__ pts, float* __restrict__ x0,
                  float* __restrict__ sq) {
  int t = blockIdx.x * 256 + threadIdx.x;
  if (t >= BB * NN) return;
  int b = t >> 11, n = t & (NN - 1);
  const float* p = pts + (size_t)b * 3 * NN;
  float a0 = p[n], a1 = p[NN + n], a2 = p[2 * NN + n];
  float* o = x0 + (size_t)t * 3;
  o[0] = a0; o[1] = a1; o[2] = a2;
  sq[t] = a0 * a0 + a1 * a1 + a2 * a2;
}

// ---------------------------------------------------------------- pd + stripe-select
// r12 GEMM (128x128, 8x8/thread, unroll-1, VGPR~76) + fused exact per-row
// top-20 of the 128-col stripe. r13 lesson: candidate writes MUST be bursts
// into line-exclusive regions — each (row,stripe) owns 32 floats (=1 cache
// line) per buffer; results collected in scalars, written 64B+16B per group.
template <int C>
__global__ __launch_bounds__(256)
void k_pds(const float* __restrict__ Xin, int RS, const float* __restrict__ sq,
           float* __restrict__ cv, int* __restrict__ ci) {
  constexpr int CH = (C < 32) ? C : 32;
  constexpr int CHP = (CH == 3) ? 3 : 36;
  constexpr int GEMMF = 2 * 128 * CHP;
  constexpr int SELF = 64 * 136;
  constexpr int SMEMF = (GEMMF > SELF) ? GEMMF : SELF;
  __shared__ __align__(16) float smem[SMEMF];
  float* Xi = smem;
  float* Xj = smem + 128 * CHP;
  float* Sld = smem;  // reused per-half after GEMM
  int b = blockIdx.z;
  int i0 = blockIdx.x * 128, j0 = blockIdx.y * 128;
  const float* Xb = Xin + (size_t)b * NN * RS;
  int tid = threadIdx.x;
  int ti = tid & 15, tj = tid >> 4;
  int w = tid >> 6, lane = tid & 63;
  float acc[8][8] = {};
  for (int c0 = 0; c0 < C; c0 += CH) {
    __syncthreads();
    if constexpr (CH == 32) {
      for (int t = tid; t < 128 * 8; t += 256) {
        int r = t >> 3, c = (t & 7) * 4;
        *(float4*)&Xi[r * CHP + c] =
            *(const float4*)&Xb[(size_t)(i0 + r) * RS + c0 + c];
        *(float4*)&Xj[r * CHP + c] =
            *(const float4*)&Xb[(size_t)(j0 + r) * RS + c0 + c];
      }
    } else {
      for (int t = tid; t < 128 * CH; t += 256) {
        int r = t / CH, c = t % CH;
        Xi[r * CHP + c] = Xb[(size_t)(i0 + r) * RS + c0 + c];
        Xj[r * CHP + c] = Xb[(size_t)(j0 + r) * RS + c0 + c];
      }
    }
    __syncthreads();
    if constexpr (CH % 4 == 0) {
      #pragma unroll 1
      for (int c = 0; c < CH; c += 4) {
        float4 ap[8], wq[8];
        #pragma unroll
        for (int p = 0; p < 8; p++)
          ap[p] = *(const float4*)&Xi[(ti + 16 * p) * CHP + c];
        #pragma unroll
        for (int q = 0; q < 8; q++)
          wq[q] = *(const float4*)&Xj[((q >> 2) * 64 + tj * 4 + (q & 3)) * CHP + c];
        #pragma unroll
        for (int p = 0; p < 8; p++)
          #pragma unroll
          for (int q = 0; q < 8; q++)
            acc[p][q] += ap[p].x * wq[q].x + ap[p].y * wq[q].y +
                         ap[p].z * wq[q].z + ap[p].w * wq[q].w;
      }
    } else {
      #pragma unroll 1
      for (int c = 0; c < CH; ++c) {
        float a[8], wv_[8];
        #pragma unroll
        for (int p = 0; p < 8; p++) a[p] = Xi[(ti + 16 * p) * CHP + c];
        #pragma unroll
        for (int q = 0; q < 8; q++)
          wv_[q] = Xj[((q >> 2) * 64 + tj * 4 + (q & 3)) * CHP + c];
        #pragma unroll
        for (int p = 0; p < 8; p++)
          #pragma unroll
          for (int q = 0; q < 8; q++) acc[p][q] += a[p] * wv_[q];
      }
    }
  }
  // sq for this thread's j columns
  const float* sqb = sq + (size_t)b * NN;
  float4 sq4[2];
  sq4[0] = *(const float4*)&sqb[j0 + tj * 4];
  sq4[1] = *(const float4*)&sqb[j0 + 64 + tj * 4];
  int t16 = lane & 15;
  #pragma unroll 1
  for (int half = 0; half < 2; ++half) {
    __syncthreads();  // prior Sld/Xi/Xj reads complete
    // stage this half's 64 rows of scores into Sld[64][136]
    #pragma unroll
    for (int pp = 0; pp < 4; ++pp) {
      int p = half * 4 + pp;
      int row = ti + 16 * pp;  // 0..63
      #pragma unroll
      for (int qh = 0; qh < 2; ++qh) {
        float4 o;
        o.x = 2.f * acc[p][qh * 4 + 0] - sq4[qh].x;
        o.y = 2.f * acc[p][qh * 4 + 1] - sq4[qh].y;
        o.z = 2.f * acc[p][qh * 4 + 2] - sq4[qh].z;
        o.w = 2.f * acc[p][qh * 4 + 3] - sq4[qh].w;
        *(float4*)&Sld[row * 136 + qh * 64 + tj * 4] = o;
      }
    }
    __syncthreads();
    // stripe top-20: wave w, 4 batches, each 16-lane group owns one row
    #pragma unroll 1
    for (int bt = 0; bt < 4; ++bt) {
      int lrow = w * 16 + bt * 4 + (lane >> 4);
      float rv[8];
      #pragma unroll
      for (int m = 0; m < 8; m++) rv[m] = Sld[lrow * 136 + m * 16 + t16];
      unsigned rem = 0u;
      int gi = i0 + half * 64 + lrow;
      size_t obase = (((size_t)b * NN + gi) * 16 + blockIdx.y) * 32;
      float myv0 = 0.f, myv1 = 0.f;
      int myi0 = 0, myi1 = 0;
      for (int k = 0; k < KNN; k++) {
        float lv = -INFINITY;
        int lm = 0;
        #pragma unroll
        for (int m = 0; m < 8; m++) {
          float vvv = ((rem >> m) & 1u) ? -INFINITY : rv[m];
          if (vvv > lv) { lv = vvv; lm = m; }  // ascending m = ascending j
        }
        float bvv = lv;
        int bj = lm * 16 + t16;  // col in stripe
        #pragma unroll
        for (int off = 8; off; off >>= 1) {
          float ov = __shfl_xor(bvv, off, 16);
          int oj = __shfl_xor(bj, off, 16);
          if (ov > bvv || (ov == bvv && oj < bj)) { bvv = ov; bj = oj; }
        }
        if (t16 == (bj & 15)) rem |= 1u << (bj >> 4);
        // collect into scalars (no runtime-indexed array -> no scratch)
        if (k < 16) {
          if (t16 == k) { myv0 = bvv; myi0 = j0 + bj; }
        } else {
          if (t16 == k - 16) { myv1 = bvv; myi1 = j0 + bj; }
        }
      }
      // burst write: 64B contiguous + 16B, one exclusive 128B line per buffer
      cv[obase + t16] = myv0;
      ci[obase + t16] = myi0;
      if (t16 < 4) {
        cv[obase + 16 + t16] = myv1;
        ci[obase + 16 + t16] = myi1;
      }
    }
  }
}

// ---------------------------------------------------------------- merge select
// one wave per row: exact top-20 of the 16 stripes' candidates (val desc,
// idx asc). Padded layout: 16 stripes x 32 slots (20 valid) = 512/row.
__global__ __launch_bounds__(256)
void k_msel(const float* __restrict__ cv, const int* __restrict__ ci,
            int* __restrict__ idx) {
  int wave = threadIdx.x >> 6, lane = threadIdx.x & 63;
  size_t r = (size_t)blockIdx.x * 4 + wave;
  const float* cvr = cv + r * 512;
  const int* cir = ci + r * 512;
  float mv[8];
  int mi[8];
  #pragma unroll
  for (int m = 0; m < 8; m++) {
    int s = m * 64 + lane;
    bool valid = (s & 31) < 20;
    mv[m] = valid ? cvr[s] : -INFINITY;
    mi[m] = valid ? cir[s] : 0x7FFFFFFF;
  }
  unsigned rem = 0u;
  int* out = idx + r * KNN;
  for (int k = 0; k < KNN; k++) {
    float lv = -INFINITY;
    int lj = 0x7FFFFFFF, lm = 0;
    #pragma unroll
    for (int m = 0; m < 8; m++) {
      if (!((rem >> m) & 1u)) {
        float vv = mv[m];
        int jj = mi[m];
        if (vv > lv || (vv == lv && jj < lj)) { lv = vv; lj = jj; lm = m; }
      }
    }
    float bv = lv;
    int bj = lj;
    int bp = (lm << 6) | lane;
    #pragma unroll
    for (int off = 32; off; off >>= 1) {
      float ov = __shfl_xor(bv, off, 64);
      int oj = __shfl_xor(bj, off, 64);
      int op = __shfl_xor(bp, off, 64);
      if (ov > bv || (ov == bv && oj < bj)) { bv = ov; bj = oj; bp = op; }
    }
    if (lane == (bp & 63)) rem |= 1u << (bp >> 6);
    if (lane == 0) out[k] = bj;
  }
}

// ---------------------------------------------------------------- y/v gemm
template <int C, int O>
__global__ __launch_bounds__(256)
void k_yv(const float* __restrict__ Xin, int RS, const float* __restrict__ W,
          const float* __restrict__ g, const float* __restrict__ bbn,
          float* __restrict__ y, float* __restrict__ v) {
  constexpr int CH = (C < 32) ? C : 32;
  constexpr int CHP = (CH == 3) ? 3 : 36;
  __shared__ __align__(16) float Xs[64 * CHP];
  __shared__ __align__(16) float Wa[64 * CHP];
  __shared__ __align__(16) float Wd[64 * CHP];
  int r0 = blockIdx.x * 64, o0 = blockIdx.y * 64;
  int ti = threadIdx.x & 15, tj = threadIdx.x >> 4;
  float ay[4][4] = {}, av[4][4] = {};
  for (int c0 = 0; c0 < C; c0 += CH) {
    if constexpr (CH == 32) {
      for (int t = threadIdx.x; t < 64 * 8; t += 256) {
        int r = t >> 3, c = (t & 7) * 4;
        *(float4*)&Xs[r * CHP + c] =
            *(const float4*)&Xin[(size_t)(r0 + r) * RS + c0 + c];
        const float* wr = W + (size_t)(o0 + r) * (2 * C) + c0 + c;
        float4 wa4 = *(const float4*)wr;
        float4 wb4 = *(const float4*)(wr + C);
        *(float4*)&Wa[r * CHP + c] = wa4;
        float4 wd4;
        wd4.x = wb4.x - wa4.x; wd4.y = wb4.y - wa4.y;
        wd4.z = wb4.z - wa4.z; wd4.w = wb4.w - wa4.w;
        *(float4*)&Wd[r * CHP + c] = wd4;
      }
    } else {
      for (int t = threadIdx.x; t < 64 * CH; t += 256) {
        int r = t / CH, c = t % CH;
        Xs[r * CHP + c] = Xin[(size_t)(r0 + r) * RS + c0 + c];
        const float* wr = W + (size_t)(o0 + r) * (2 * C) + c0 + c;
        float wa_ = wr[0];
        Wa[r * CHP + c] = wa_;
        Wd[r * CHP + c] = wr[C] - wa_;
      }
    }
    __syncthreads();
    if constexpr (CH % 4 == 0) {
      #pragma unroll
      for (int c = 0; c < CH; c += 4) {
        float4 ap[4], qa[4], qd[4];
        #pragma unroll
        for (int p = 0; p < 4; p++)
          ap[p] = *(const float4*)&Xs[(ti + 16 * p) * CHP + c];
        #pragma unroll
        for (int q = 0; q < 4; q++) {
          qa[q] = *(const float4*)&Wa[(tj * 4 + q) * CHP + c];
          qd[q] = *(const float4*)&Wd[(tj * 4 + q) * CHP + c];
        }
        #pragma unroll
        for (int p = 0; p < 4; p++)
          #pragma unroll
          for (int q = 0; q < 4; q++) {
            ay[p][q] += ap[p].x * qa[q].x + ap[p].y * qa[q].y +
                        ap[p].z * qa[q].z + ap[p].w * qa[q].w;
            av[p][q] += ap[p].x * qd[q].x + ap[p].y * qd[q].y +
                        ap[p].z * qd[q].z + ap[p].w * qd[q].w;
          }
      }
    } else {
      #pragma unroll
      for (int c = 0; c < CH; ++c) {
        float a[4];
        #pragma unroll
        for (int p = 0; p < 4; p++) a[p] = Xs[(ti + 16 * p) * CHP + c];
        #pragma unroll
        for (int q = 0; q < 4; q++) {
          float wa_ = Wa[(tj * 4 + q) * CHP + c];
          float wd_ = Wd[(tj * 4 + q) * CHP + c];
          #pragma unroll
          for (int p = 0; p < 4; p++) {
            ay[p][q] += a[p] * wa_;
            av[p][q] += a[p] * wd_;
          }
        }
      }
    }
    __syncthreads();
  }
  #pragma unroll
  for (int p = 0; p < 4; p++) {
    int row = r0 + ti + 16 * p;
    float oy[4], ov[4];
    #pragma unroll
    for (int q = 0; q < 4; q++) {
      int o = o0 + tj * 4 + q;
      float s = BN_INV * g[o];
      oy[q] = s * ay[p][q];
      ov[q] = s * av[p][q] + bbn[o];
    }
    *(float4*)&y[(size_t)row * O + o0 + tj * 4] = *(float4*)oy;
    *(float4*)&v[(size_t)row * O + o0 + tj * 4] = *(float4*)ov;
  }
}

// ---------------------------------------------------------------- aggregate
template <int O, bool DO_SQ>
__global__ __launch_bounds__(256)
void k_agg(const float* __restrict__ y, const float* __restrict__ v,
           const int* __restrict__ idx, float* __restrict__ cat_out, int coloff,
           float* __restrict__ sqo) {
  constexpr int RPB = 256 / O;
  int rl = threadIdx.x / O;
  int o = threadIdx.x % O;
  int row = blockIdx.x * RPB + rl;  // b*N+n
  int b = row >> 11;
  const int* ix = idx + (size_t)row * KNN;
  float vv = v[(size_t)row * O + o];
  const float* yb = y + (size_t)b * NN * O;
  float m = -INFINITY;
  #pragma unroll
  for (int k = 0; k < KNN; k++) {
    int j = ix[k];
    m = fmaxf(m, yb[(size_t)j * O + o] + vv);
  }
  float out = m >= 0.f ? m : 0.2f * m;
  cat_out[(size_t)row * 512 + coloff + o] = out;
  if constexpr (DO_SQ) {
    constexpr int WPR = O / 64;
    float p2 = out * out;
    #pragma unroll
    for (int off = 32; off; off >>= 1) p2 += __shfl_xor(p2, off, 64);
    __shared__ float part[4];
    int wv = threadIdx.x >> 6;
    if ((threadIdx.x & 63) == 0) part[wv] = p2;
    __syncthreads();
    if ((threadIdx.x % O) == 0) {
      int w0 = threadIdx.x >> 6;
      float s = 0.f;
      #pragma unroll
      for (int w = 0; w < WPR; ++w) s += part[w0 + w];
      sqo[row] = s;
    }
  }
}

// ---------------------------------------------------------------- h5 + reduce
__global__ __launch_bounds__(256)
void k_h5r(const float* __restrict__ A, const float* __restrict__ W5,
           const float* __restrict__ g, const float* __restrict__ bbn,
           float* __restrict__ pm, float* __restrict__ ps) {
  __shared__ __align__(16) __bf16 Al[128 * 64];
  __shared__ __align__(16) __bf16 Bl[128 * 64];
  __shared__ float smax[2][128];
  __shared__ float ssum[2][128];
  int m0 = blockIdx.x * 128, o0 = blockIdx.y * 128;
  int w = threadIdx.x >> 6, lane = threadIdx.x & 63;
  int wm = w >> 1, wn = w & 1;
  f32x4 acc[4][4];
  #pragma unroll
  for (int f = 0; f < 4; f++)
    #pragma unroll
    for (int j = 0; j < 4; j++) acc[f][j] = (f32x4){0.f, 0.f, 0.f, 0.f};

  int wr0 = w * 32;
  int c8 = lane & 15;
  for (int k0 = 0; k0 < 512; k0 += 64) {
    #pragma unroll
    for (int i = 0; i < 8; i++) {
      int row = wr0 + i * 4 + (lane >> 4);
      float4 a4 = *(const float4*)&A[(size_t)(m0 + row) * 512 + k0 + c8 * 4];
      float4 b4 = *(const float4*)&W5[(size_t)(o0 + row) * 512 + k0 + c8 * 4];
      int el = (c8 * 4) ^ ((row & 7) << 3);
      bf16x4 ah, bh;
      ah.x = (__bf16)a4.x; ah.y = (__bf16)a4.y; ah.z = (__bf16)a4.z; ah.w = (__bf16)a4.w;
      bh.x = (__bf16)b4.x; bh.y = (__bf16)b4.y; bh.z = (__bf16)b4.z; bh.w = (__bf16)b4.w;
      *(bf16x4*)&Al[row * 64 + el] = ah;
      *(bf16x4*)&Bl[row * 64 + el] = bh;
    }
    __syncthreads();
    #pragma unroll
    for (int kk = 0; kk < 2; kk++) {
      bf16x8 af[4], bfr[4];
      int cb = (lane >> 4) + kk * 4;
      #pragma unroll
      for (int f = 0; f < 4; f++) {
        int ra = wm * 64 + f * 16 + (lane & 15);
        af[f] = *(const bf16x8*)&Al[ra * 64 + ((cb ^ (ra & 7)) * 8)];
        int rb = wn * 64 + f * 16 + (lane & 15);
        bfr[f] = *(const bf16x8*)&Bl[rb * 64 + ((cb ^ (rb & 7)) * 8)];
      }
      #pragma unroll
      for (int f = 0; f < 4; f++)
        #pragma unroll
        for (int j = 0; j < 4; j++)
          acc[f][j] = __builtin_amdgcn_mfma_f32_16x16x32_bf16(af[f], bfr[j],
                                                              acc[f][j], 0, 0, 0);
    }
    __syncthreads();
  }
  #pragma unroll
  for (int j = 0; j < 4; j++) {
    int o = o0 + wn * 64 + j * 16 + (lane & 15);
    float s = BN_INV * g[o], bb = bbn[o];
    float mx = -INFINITY, sm = 0.f;
    #pragma unroll
    for (int f = 0; f < 4; f++)
      #pragma unroll
      for (int r = 0; r < 4; r++) {
        float z = s * acc[f][j][r] + bb;
        z = z >= 0.f ? z : 0.2f * z;
        mx = fmaxf(mx, z);
        sm += z;
      }
    mx = fmaxf(mx, __shfl_xor(mx, 16, 64)); sm += __shfl_xor(sm, 16, 64);
    mx = fmaxf(mx, __shfl_xor(mx, 32, 64)); sm += __shfl_xor(sm, 32, 64);
    if ((lane >> 4) == 0) {
      int cl = wn * 64 + j * 16 + (lane & 15);
      smax[wm][cl] = mx;
      ssum[wm][cl] = sm;
    }
  }
  __syncthreads();
  if (threadIdx.x < 128) {
    float m = fmaxf(smax[0][threadIdx.x], smax[1][threadIdx.x]);
    float sv = ssum[0][threadIdx.x] + ssum[1][threadIdx.x];
    pm[(size_t)blockIdx.x * 1024 + o0 + threadIdx.x] = m;
    ps[(size_t)blockIdx.x * 1024 + o0 + threadIdx.x] = sv;
  }
}

// ---------------------------------------------------------------- reductions
__global__ __launch_bounds__(256)
void k_red2(const float* __restrict__ pm, const float* __restrict__ ps,
            float* __restrict__ feat) {
  int gg = blockIdx.x * 256 + threadIdx.x;
  if (gg >= BB * 1024) return;
  int b = gg >> 10, o = gg & 1023;
  float m = -INFINITY, s = 0.f;
  for (int t = 0; t < 16; ++t) {
    m = fmaxf(m, pm[(size_t)(b * 16 + t) * 1024 + o]);
    s += ps[(size_t)(b * 16 + t) * 1024 + o];
  }
  feat[(size_t)b * 2048 + o] = m;
  feat[(size_t)b * 2048 + 1024 + o] = s * (1.f / 2048.f);
}

// ---------------------------------------------------------------- FC layers
__global__ __launch_bounds__(256)
void k_fc(const float* __restrict__ in, const float* __restrict__ W,
          const float* __restrict__ g, const float* __restrict__ bbn,
          const float* __restrict__ eb, float* __restrict__ out, int IN, int O,
          int mode) {
  int gid = (blockIdx.x * 256 + threadIdx.x) >> 6;
  int lane = threadIdx.x & 63;
  int b = gid / O, o = gid % O;
  if (b >= BB) return;
  const float* ip = in + (size_t)b * IN;
  const float* wp = W + (size_t)o * IN;
  float acc = 0.f;
  for (int i = lane; i < IN; i += 64) acc += ip[i] * wp[i];
  #pragma unroll
  for (int off = 32; off; off >>= 1) acc += __shfl_xor(acc, off, 64);
  if (lane == 0) {
    float z;
    if (mode == 0) {
      z = BN_INV * g[o] * acc + bbn[o];
      z = z >= 0.f ? z : 0.2f * z;
    } else if (mode == 1) {
      z = BN_INV * g[o] * (acc + eb[o]) + bbn[o];
      z = z >= 0.f ? z : 0.2f * z;
    } else {
      z = acc + eb[o];
    }
    out[(size_t)b * O + o] = z;
  }
}

// ---------------------------------------------------------------- host
extern "C" void kernel_launch(void* const* d_in, const int* in_sizes, int n_in,
                              void* d_out, int out_size, void* d_ws,
                              size_t ws_size, hipStream_t stream) {
  (void)in_sizes; (void)n_in; (void)out_size; (void)ws_size;
  const float* pts = (const float*)d_in[0];
  const float* W1 = (const float*)d_in[1];
  const float* g1 = (const float*)d_in[2];
  const float* b1 = (const float*)d_in[3];
  const float* W2 = (const float*)d_in[4];
  const float* g2 = (const float*)d_in[5];
  const float* b2 = (const float*)d_in[6];
  const float* W3 = (const float*)d_in[7];
  const float* g3 = (const float*)d_in[8];
  const float* b3 = (const float*)d_in[9];
  const float* W4 = (const float*)d_in[10];
  const float* g4 = (const float*)d_in[11];
  const float* b4 = (const float*)d_in[12];
  const float* W5 = (const float*)d_in[13];
  const float* g5 = (const float*)d_in[14];
  const float* b5 = (const float*)d_in[15];
  const float* Wl1 = (const float*)d_in[16];
  const float* g6 = (const float*)d_in[17];
  const float* b6 = (const float*)d_in[18];
  const float* Wl2 = (const float*)d_in[19];
  const float* bl2 = (const float*)d_in[20];
  const float* g7 = (const float*)d_in[21];
  const float* b7 = (const float*)d_in[22];
  const float* Wl3 = (const float*)d_in[23];
  const float* bl3 = (const float*)d_in[24];

  char* ws = (char*)d_ws;
  float* x0 = (float*)(ws + 0);                  // 196608
  float* cat = (float*)(ws + 196608);            // 33554432
  float* sq = (float*)(ws + 33751040);           // 65536
  int* idx = (int*)(ws + 33816576);              // 1310720
  float* y = (float*)(ws + 35127296);            // 16777216
  float* v = (float*)(ws + 51904512);            // 16777216
  float* pm = (float*)(ws + 68681728);           // 524288
  float* ps = (float*)(ws + 69206016);           // 524288
  float* feat = (float*)(ws + 69730304);         // 65536
  float* fc1o = (float*)(ws + 69795840);         // 16384
  float* fc2o = (float*)(ws + 69812224);         // 8192
  float* cv = (float*)(ws + 69820416);           // 33554432 (16384*512*4)
  int* ci = (int*)(ws + 103374848);              // 33554432

  k_unscramble<<<dim3(64), 256, 0, stream>>>(pts, x0, sq);

  // ---- layer 1: C=3 O=64
  k_pds<3><<<dim3(16, 16, BB), 256, 0, stream>>>(x0, 3, sq, cv, ci);
  k_msel<<<dim3(BB * NN / 4), 256, 0, stream>>>(cv, ci, idx);
  k_yv<3, 64><<<dim3(256, 1), 256, 0, stream>>>(x0, 3, W1, g1, b1, y, v);
  k_agg<64, true><<<dim3(BB * NN / 4), 256, 0, stream>>>(y, v, idx, cat, 0, sq);

  // ---- layer 2: C=64 O=64
  k_pds<64><<<dim3(16, 16, BB), 256, 0, stream>>>(cat, 512, sq, cv, ci);
  k_msel<<<dim3(BB * NN / 4), 256, 0, stream>>>(cv, ci, idx);
  k_yv<64, 64><<<dim3(256, 1), 256, 0, stream>>>(cat, 512, W2, g2, b2, y, v);
  k_agg<64, true><<<dim3(BB * NN / 4), 256, 0, stream>>>(y, v, idx, cat, 64, sq);

  // ---- layer 3: C=64 O=128
  k_pds<64><<<dim3(16, 16, BB), 256, 0, stream>>>(cat + 64, 512, sq, cv, ci);
  k_msel<<<dim3(BB * NN / 4), 256, 0, stream>>>(cv, ci, idx);
  k_yv<64, 128><<<dim3(256, 2), 256, 0, stream>>>(cat + 64, 512, W3, g3, b3, y, v);
  k_agg<128, true><<<dim3(BB * NN / 2), 256, 0, stream>>>(y, v, idx, cat, 128, sq);

  // ---- layer 4: C=128 O=256
  k_pds<128><<<dim3(16, 16, BB), 256, 0, stream>>>(cat + 128, 512, sq, cv, ci);
  k_msel<<<dim3(BB * NN / 4), 256, 0, stream>>>(cv, ci, idx);
  k_yv<128, 256><<<dim3(256, 4), 256, 0, stream>>>(cat + 128, 512, W4, g4, b4, y, v);
  k_agg<256, false><<<dim3(BB * NN), 256, 0, stream>>>(y, v, idx, cat, 256, nullptr);

  // ---- h5 (bf16 MFMA, fused max/mean partials) + feat
  k_h5r<<<dim3(128, 8), 256, 0, stream>>>(cat, W5, g5, b5, pm, ps);
  k_red2<<<dim3(32), 256, 0, stream>>>(pm, ps, feat);

  // ---- FC head
  k_fc<<<dim3(1024), 256, 0, stream>>>(feat, Wl1, g6, b6, nullptr, fc1o, 2048, 512, 0);
  k_fc<<<dim3(512), 256, 0, stream>>>(fc1o, Wl2, g7, b7, bl2, fc2o, 512, 256, 1);
  k_fc<<<dim3(80), 256, 0, stream>>>(fc2o, Wl3, nullptr, nullptr, bl3, (float*)d_out, 256, 40, 2);
}

// Round 15
// 1802.035 us; speedup vs baseline: 1.0855x; 1.0855x over previous
//
#include <hip/hip_runtime.h>
#include <math.h>

#define BB 8
#define NN 2048
#define KNN 20
#define BN_INV 0.9999950000374997f

typedef __bf16 bf16x8 __attribute__((ext_vector_type(8)));
typedef __bf16 bf16x4 __attribute__((ext_vector_type(4)));
typedef float f32x4 __attribute__((ext_vector_type(4)));

// ---------------------------------------------------------------- unscramble
__global__ __launch_bounds__(256)
void k_unscramble(const float* __restrict__ pts, float* __restrict__ x0,
                  float* __restrict__ sq) {
  int t = blockIdx.x * 256 + threadIdx.x;
  if (t >= BB * NN) return;
  int b = t >> 11, n = t & (NN - 1);
  const float* p = pts + (size_t)b * 3 * NN;
  float a0 = p[n], a1 = p[NN + n], a2 = p[2 * NN + n];
  float* o = x0 + (size_t)t * 3;
  o[0] = a0; o[1] = a1; o[2] = a2;
  sq[t] = a0 * a0 + a1 * a1 + a2 * a2;
}

// ---------------------------------------------------------------- pd + stripe-select
// r12 GEMM (128x128, 8x8/thread, unroll-1 c-loop) + fused exact per-row
// top-20 of the 128-col stripe. r14 lesson (rule #20): the half-loop MUST be
// fully unrolled — runtime `half` indexing acc[][] sent the accumulators to
// scratch (670MB/dispatch of hidden traffic, r13/r14 counters identical).
template <int C>
__global__ __launch_bounds__(256)
void k_pds(const float* __restrict__ Xin, int RS, const float* __restrict__ sq,
           float* __restrict__ cv, int* __restrict__ ci) {
  constexpr int CH = (C < 32) ? C : 32;
  constexpr int CHP = (CH == 3) ? 3 : 36;
  constexpr int GEMMF = 2 * 128 * CHP;
  constexpr int SELF = 64 * 136;
  constexpr int SMEMF = (GEMMF > SELF) ? GEMMF : SELF;
  __shared__ __align__(16) float smem[SMEMF];
  float* Xi = smem;
  float* Xj = smem + 128 * CHP;
  float* Sld = smem;  // reused per-half after GEMM
  int b = blockIdx.z;
  int i0 = blockIdx.x * 128, j0 = blockIdx.y * 128;
  const float* Xb = Xin + (size_t)b * NN * RS;
  int tid = threadIdx.x;
  int ti = tid & 15, tj = tid >> 4;
  int w = tid >> 6, lane = tid & 63;
  float acc[8][8] = {};
  for (int c0 = 0; c0 < C; c0 += CH) {
    __syncthreads();
    if constexpr (CH == 32) {
      for (int t = tid; t < 128 * 8; t += 256) {
        int r = t >> 3, c = (t & 7) * 4;
        *(float4*)&Xi[r * CHP + c] =
            *(const float4*)&Xb[(size_t)(i0 + r) * RS + c0 + c];
        *(float4*)&Xj[r * CHP + c] =
            *(const float4*)&Xb[(size_t)(j0 + r) * RS + c0 + c];
      }
    } else {
      for (int t = tid; t < 128 * CH; t += 256) {
        int r = t / CH, c = t % CH;
        Xi[r * CHP + c] = Xb[(size_t)(i0 + r) * RS + c0 + c];
        Xj[r * CHP + c] = Xb[(size_t)(j0 + r) * RS + c0 + c];
      }
    }
    __syncthreads();
    if constexpr (CH % 4 == 0) {
      #pragma unroll 1
      for (int c = 0; c < CH; c += 4) {
        float4 ap[8], wq[8];
        #pragma unroll
        for (int p = 0; p < 8; p++)
          ap[p] = *(const float4*)&Xi[(ti + 16 * p) * CHP + c];
        #pragma unroll
        for (int q = 0; q < 8; q++)
          wq[q] = *(const float4*)&Xj[((q >> 2) * 64 + tj * 4 + (q & 3)) * CHP + c];
        #pragma unroll
        for (int p = 0; p < 8; p++)
          #pragma unroll
          for (int q = 0; q < 8; q++)
            acc[p][q] += ap[p].x * wq[q].x + ap[p].y * wq[q].y +
                         ap[p].z * wq[q].z + ap[p].w * wq[q].w;
      }
    } else {
      #pragma unroll 1
      for (int c = 0; c < CH; ++c) {
        float a[8], wv_[8];
        #pragma unroll
        for (int p = 0; p < 8; p++) a[p] = Xi[(ti + 16 * p) * CHP + c];
        #pragma unroll
        for (int q = 0; q < 8; q++)
          wv_[q] = Xj[((q >> 2) * 64 + tj * 4 + (q & 3)) * CHP + c];
        #pragma unroll
        for (int p = 0; p < 8; p++)
          #pragma unroll
          for (int q = 0; q < 8; q++) acc[p][q] += a[p] * wv_[q];
      }
    }
  }
  // sq for this thread's j columns
  const float* sqb = sq + (size_t)b * NN;
  float4 sq4[2];
  sq4[0] = *(const float4*)&sqb[j0 + tj * 4];
  sq4[1] = *(const float4*)&sqb[j0 + 64 + tj * 4];
  int t16 = lane & 15;
  #pragma unroll
  for (int half = 0; half < 2; ++half) {   // FULL unroll: acc indices static
    __syncthreads();  // prior Sld/Xi/Xj reads complete
    // stage this half's 64 rows of scores into Sld[64][136]
    #pragma unroll
    for (int pp = 0; pp < 4; ++pp) {
      int p = half * 4 + pp;
      int row = ti + 16 * pp;  // 0..63
      #pragma unroll
      for (int qh = 0; qh < 2; ++qh) {
        float4 o;
        o.x = 2.f * acc[p][qh * 4 + 0] - sq4[qh].x;
        o.y = 2.f * acc[p][qh * 4 + 1] - sq4[qh].y;
        o.z = 2.f * acc[p][qh * 4 + 2] - sq4[qh].z;
        o.w = 2.f * acc[p][qh * 4 + 3] - sq4[qh].w;
        *(float4*)&Sld[row * 136 + qh * 64 + tj * 4] = o;
      }
    }
    __syncthreads();
    // stripe top-20: wave w, 4 batches, each 16-lane group owns one row
    #pragma unroll 1
    for (int bt = 0; bt < 4; ++bt) {
      int lrow = w * 16 + bt * 4 + (lane >> 4);
      float rv[8];
      #pragma unroll
      for (int m = 0; m < 8; m++) rv[m] = Sld[lrow * 136 + m * 16 + t16];
      unsigned rem = 0u;
      int gi = i0 + half * 64 + lrow;
      size_t obase = (((size_t)b * NN + gi) * 16 + blockIdx.y) * 32;
      float myv0 = 0.f, myv1 = 0.f;
      int myi0 = 0, myi1 = 0;
      for (int k = 0; k < KNN; k++) {
        float lv = -INFINITY;
        int lm = 0;
        #pragma unroll
        for (int m = 0; m < 8; m++) {
          float vvv = ((rem >> m) & 1u) ? -INFINITY : rv[m];
          if (vvv > lv) { lv = vvv; lm = m; }  // ascending m = ascending j
        }
        float bvv = lv;
        int bj = lm * 16 + t16;  // col in stripe
        #pragma unroll
        for (int off = 8; off; off >>= 1) {
          float ov = __shfl_xor(bvv, off, 16);
          int oj = __shfl_xor(bj, off, 16);
          if (ov > bvv || (ov == bvv && oj < bj)) { bvv = ov; bj = oj; }
        }
        if (t16 == (bj & 15)) rem |= 1u << (bj >> 4);
        // collect into scalars (no runtime-indexed array -> no scratch)
        if (k < 16) {
          if (t16 == k) { myv0 = bvv; myi0 = j0 + bj; }
        } else {
          if (t16 == k - 16) { myv1 = bvv; myi1 = j0 + bj; }
        }
      }
      // burst write: 64B contiguous + 16B, one exclusive 128B line per buffer
      cv[obase + t16] = myv0;
      ci[obase + t16] = myi0;
      if (t16 < 4) {
        cv[obase + 16 + t16] = myv1;
        ci[obase + 16 + t16] = myi1;
      }
    }
  }
}

// ---------------------------------------------------------------- merge select
// one wave per row: exact top-20 of the 16 stripes' candidates (val desc,
// idx asc). Padded layout: 16 stripes x 32 slots (20 valid) = 512/row.
__global__ __launch_bounds__(256)
void k_msel(const float* __restrict__ cv, const int* __restrict__ ci,
            int* __restrict__ idx) {
  int wave = threadIdx.x >> 6, lane = threadIdx.x & 63;
  size_t r = (size_t)blockIdx.x * 4 + wave;
  const float* cvr = cv + r * 512;
  const int* cir = ci + r * 512;
  float mv[8];
  int mi[8];
  #pragma unroll
  for (int m = 0; m < 8; m++) {
    int s = m * 64 + lane;
    bool valid = (s & 31) < 20;
    mv[m] = valid ? cvr[s] : -INFINITY;
    mi[m] = valid ? cir[s] : 0x7FFFFFFF;
  }
  unsigned rem = 0u;
  int* out = idx + r * KNN;
  for (int k = 0; k < KNN; k++) {
    float lv = -INFINITY;
    int lj = 0x7FFFFFFF, lm = 0;
    #pragma unroll
    for (int m = 0; m < 8; m++) {
      if (!((rem >> m) & 1u)) {
        float vv = mv[m];
        int jj = mi[m];
        if (vv > lv || (vv == lv && jj < lj)) { lv = vv; lj = jj; lm = m; }
      }
    }
    float bv = lv;
    int bj = lj;
    int bp = (lm << 6) | lane;
    #pragma unroll
    for (int off = 32; off; off >>= 1) {
      float ov = __shfl_xor(bv, off, 64);
      int oj = __shfl_xor(bj, off, 64);
      int op = __shfl_xor(bp, off, 64);
      if (ov > bv || (ov == bv && oj < bj)) { bv = ov; bj = oj; bp = op; }
    }
    if (lane == (bp & 63)) rem |= 1u << (bp >> 6);
    if (lane == 0) out[k] = bj;
  }
}

// ---------------------------------------------------------------- y/v gemm
template <int C, int O>
__global__ __launch_bounds__(256)
void k_yv(const float* __restrict__ Xin, int RS, const float* __restrict__ W,
          const float* __restrict__ g, const float* __restrict__ bbn,
          float* __restrict__ y, float* __restrict__ v) {
  constexpr int CH = (C < 32) ? C : 32;
  constexpr int CHP = (CH == 3) ? 3 : 36;
  __shared__ __align__(16) float Xs[64 * CHP];
  __shared__ __align__(16) float Wa[64 * CHP];
  __shared__ __align__(16) float Wd[64 * CHP];
  int r0 = blockIdx.x * 64, o0 = blockIdx.y * 64;
  int ti = threadIdx.x & 15, tj = threadIdx.x >> 4;
  float ay[4][4] = {}, av[4][4] = {};
  for (int c0 = 0; c0 < C; c0 += CH) {
    if constexpr (CH == 32) {
      for (int t = threadIdx.x; t < 64 * 8; t += 256) {
        int r = t >> 3, c = (t & 7) * 4;
        *(float4*)&Xs[r * CHP + c] =
            *(const float4*)&Xin[(size_t)(r0 + r) * RS + c0 + c];
        const float* wr = W + (size_t)(o0 + r) * (2 * C) + c0 + c;
        float4 wa4 = *(const float4*)wr;
        float4 wb4 = *(const float4*)(wr + C);
        *(float4*)&Wa[r * CHP + c] = wa4;
        float4 wd4;
        wd4.x = wb4.x - wa4.x; wd4.y = wb4.y - wa4.y;
        wd4.z = wb4.z - wa4.z; wd4.w = wb4.w - wa4.w;
        *(float4*)&Wd[r * CHP + c] = wd4;
      }
    } else {
      for (int t = threadIdx.x; t < 64 * CH; t += 256) {
        int r = t / CH, c = t % CH;
        Xs[r * CHP + c] = Xin[(size_t)(r0 + r) * RS + c0 + c];
        const float* wr = W + (size_t)(o0 + r) * (2 * C) + c0 + c;
        float wa_ = wr[0];
        Wa[r * CHP + c] = wa_;
        Wd[r * CHP + c] = wr[C] - wa_;
      }
    }
    __syncthreads();
    if constexpr (CH % 4 == 0) {
      #pragma unroll
      for (int c = 0; c < CH; c += 4) {
        float4 ap[4], qa[4], qd[4];
        #pragma unroll
        for (int p = 0; p < 4; p++)
          ap[p] = *(const float4*)&Xs[(ti + 16 * p) * CHP + c];
        #pragma unroll
        for (int q = 0; q < 4; q++) {
          qa[q] = *(const float4*)&Wa[(tj * 4 + q) * CHP + c];
          qd[q] = *(const float4*)&Wd[(tj * 4 + q) * CHP + c];
        }
        #pragma unroll
        for (int p = 0; p < 4; p++)
          #pragma unroll
          for (int q = 0; q < 4; q++) {
            ay[p][q] += ap[p].x * qa[q].x + ap[p].y * qa[q].y +
                        ap[p].z * qa[q].z + ap[p].w * qa[q].w;
            av[p][q] += ap[p].x * qd[q].x + ap[p].y * qd[q].y +
                        ap[p].z * qd[q].z + ap[p].w * qd[q].w;
          }
      }
    } else {
      #pragma unroll
      for (int c = 0; c < CH; ++c) {
        float a[4];
        #pragma unroll
        for (int p = 0; p < 4; p++) a[p] = Xs[(ti + 16 * p) * CHP + c];
        #pragma unroll
        for (int q = 0; q < 4; q++) {
          float wa_ = Wa[(tj * 4 + q) * CHP + c];
          float wd_ = Wd[(tj * 4 + q) * CHP + c];
          #pragma unroll
          for (int p = 0; p < 4; p++) {
            ay[p][q] += a[p] * wa_;
            av[p][q] += a[p] * wd_;
          }
        }
      }
    }
    __syncthreads();
  }
  #pragma unroll
  for (int p = 0; p < 4; p++) {
    int row = r0 + ti + 16 * p;
    float oy[4], ov[4];
    #pragma unroll
    for (int q = 0; q < 4; q++) {
      int o = o0 + tj * 4 + q;
      float s = BN_INV * g[o];
      oy[q] = s * ay[p][q];
      ov[q] = s * av[p][q] + bbn[o];
    }
    *(float4*)&y[(size_t)row * O + o0 + tj * 4] = *(float4*)oy;
    *(float4*)&v[(size_t)row * O + o0 + tj * 4] = *(float4*)ov;
  }
}

// ---------------------------------------------------------------- aggregate
template <int O, bool DO_SQ>
__global__ __launch_bounds__(256)
void k_agg(const float* __restrict__ y, const float* __restrict__ v,
           const int* __restrict__ idx, float* __restrict__ cat_out, int coloff,
           float* __restrict__ sqo) {
  constexpr int RPB = 256 / O;
  int rl = threadIdx.x / O;
  int o = threadIdx.x % O;
  int row = blockIdx.x * RPB + rl;  // b*N+n
  int b = row >> 11;
  const int* ix = idx + (size_t)row * KNN;
  float vv = v[(size_t)row * O + o];
  const float* yb = y + (size_t)b * NN * O;
  float m = -INFINITY;
  #pragma unroll
  for (int k = 0; k < KNN; k++) {
    int j = ix[k];
    m = fmaxf(m, yb[(size_t)j * O + o] + vv);
  }
  float out = m >= 0.f ? m : 0.2f * m;
  cat_out[(size_t)row * 512 + coloff + o] = out;
  if constexpr (DO_SQ) {
    constexpr int WPR = O / 64;
    float p2 = out * out;
    #pragma unroll
    for (int off = 32; off; off >>= 1) p2 += __shfl_xor(p2, off, 64);
    __shared__ float part[4];
    int wv = threadIdx.x >> 6;
    if ((threadIdx.x & 63) == 0) part[wv] = p2;
    __syncthreads();
    if ((threadIdx.x % O) == 0) {
      int w0 = threadIdx.x >> 6;
      float s = 0.f;
      #pragma unroll
      for (int w = 0; w < WPR; ++w) s += part[w0 + w];
      sqo[row] = s;
    }
  }
}

// ---------------------------------------------------------------- h5 + reduce
__global__ __launch_bounds__(256)
void k_h5r(const float* __restrict__ A, const float* __restrict__ W5,
           const float* __restrict__ g, const float* __restrict__ bbn,
           float* __restrict__ pm, float* __restrict__ ps) {
  __shared__ __align__(16) __bf16 Al[128 * 64];
  __shared__ __align__(16) __bf16 Bl[128 * 64];
  __shared__ float smax[2][128];
  __shared__ float ssum[2][128];
  int m0 = blockIdx.x * 128, o0 = blockIdx.y * 128;
  int w = threadIdx.x >> 6, lane = threadIdx.x & 63;
  int wm = w >> 1, wn = w & 1;
  f32x4 acc[4][4];
  #pragma unroll
  for (int f = 0; f < 4; f++)
    #pragma unroll
    for (int j = 0; j < 4; j++) acc[f][j] = (f32x4){0.f, 0.f, 0.f, 0.f};

  int wr0 = w * 32;
  int c8 = lane & 15;
  for (int k0 = 0; k0 < 512; k0 += 64) {
    #pragma unroll
    for (int i = 0; i < 8; i++) {
      int row = wr0 + i * 4 + (lane >> 4);
      float4 a4 = *(const float4*)&A[(size_t)(m0 + row) * 512 + k0 + c8 * 4];
      float4 b4 = *(const float4*)&W5[(size_t)(o0 + row) * 512 + k0 + c8 * 4];
      int el = (c8 * 4) ^ ((row & 7) << 3);
      bf16x4 ah, bh;
      ah.x = (__bf16)a4.x; ah.y = (__bf16)a4.y; ah.z = (__bf16)a4.z; ah.w = (__bf16)a4.w;
      bh.x = (__bf16)b4.x; bh.y = (__bf16)b4.y; bh.z = (__bf16)b4.z; bh.w = (__bf16)b4.w;
      *(bf16x4*)&Al[row * 64 + el] = ah;
      *(bf16x4*)&Bl[row * 64 + el] = bh;
    }
    __syncthreads();
    #pragma unroll
    for (int kk = 0; kk < 2; kk++) {
      bf16x8 af[4], bfr[4];
      int cb = (lane >> 4) + kk * 4;
      #pragma unroll
      for (int f = 0; f < 4; f++) {
        int ra = wm * 64 + f * 16 + (lane & 15);
        af[f] = *(const bf16x8*)&Al[ra * 64 + ((cb ^ (ra & 7)) * 8)];
        int rb = wn * 64 + f * 16 + (lane & 15);
        bfr[f] = *(const bf16x8*)&Bl[rb * 64 + ((cb ^ (rb & 7)) * 8)];
      }
      #pragma unroll
      for (int f = 0; f < 4; f++)
        #pragma unroll
        for (int j = 0; j < 4; j++)
          acc[f][j] = __builtin_amdgcn_mfma_f32_16x16x32_bf16(af[f], bfr[j],
                                                              acc[f][j], 0, 0, 0);
    }
    __syncthreads();
  }
  #pragma unroll
  for (int j = 0; j < 4; j++) {
    int o = o0 + wn * 64 + j * 16 + (lane & 15);
    float s = BN_INV * g[o], bb = bbn[o];
    float mx = -INFINITY, sm = 0.f;
    #pragma unroll
    for (int f = 0; f < 4; f++)
      #pragma unroll
      for (int r = 0; r < 4; r++) {
        float z = s * acc[f][j][r] + bb;
        z = z >= 0.f ? z : 0.2f * z;
        mx = fmaxf(mx, z);
        sm += z;
      }
    mx = fmaxf(mx, __shfl_xor(mx, 16, 64)); sm += __shfl_xor(sm, 16, 64);
    mx = fmaxf(mx, __shfl_xor(mx, 32, 64)); sm += __shfl_xor(sm, 32, 64);
    if ((lane >> 4) == 0) {
      int cl = wn * 64 + j * 16 + (lane & 15);
      smax[wm][cl] = mx;
      ssum[wm][cl] = sm;
    }
  }
  __syncthreads();
  if (threadIdx.x < 128) {
    float m = fmaxf(smax[0][threadIdx.x], smax[1][threadIdx.x]);
    float sv = ssum[0][threadIdx.x] + ssum[1][threadIdx.x];
    pm[(size_t)blockIdx.x * 1024 + o0 + threadIdx.x] = m;
    ps[(size_t)blockIdx.x * 1024 + o0 + threadIdx.x] = sv;
  }
}

// ---------------------------------------------------------------- reductions
__global__ __launch_bounds__(256)
void k_red2(const float* __restrict__ pm, const float* __restrict__ ps,
            float* __restrict__ feat) {
  int gg = blockIdx.x * 256 + threadIdx.x;
  if (gg >= BB * 1024) return;
  int b = gg >> 10, o = gg & 1023;
  float m = -INFINITY, s = 0.f;
  for (int t = 0; t < 16; ++t) {
    m = fmaxf(m, pm[(size_t)(b * 16 + t) * 1024 + o]);
    s += ps[(size_t)(b * 16 + t) * 1024 + o];
  }
  feat[(size_t)b * 2048 + o] = m;
  feat[(size_t)b * 2048 + 1024 + o] = s * (1.f / 2048.f);
}

// ---------------------------------------------------------------- FC layers
__global__ __launch_bounds__(256)
void k_fc(const float* __restrict__ in, const float* __restrict__ W,
          const float* __restrict__ g, const float* __restrict__ bbn,
          const float* __restrict__ eb, float* __restrict__ out, int IN, int O,
          int mode) {
  int gid = (blockIdx.x * 256 + threadIdx.x) >> 6;
  int lane = threadIdx.x & 63;
  int b = gid / O, o = gid % O;
  if (b >= BB) return;
  const float* ip = in + (size_t)b * IN;
  const float* wp = W + (size_t)o * IN;
  float acc = 0.f;
  for (int i = lane; i < IN; i += 64) acc += ip[i] * wp[i];
  #pragma unroll
  for (int off = 32; off; off >>= 1) acc += __shfl_xor(acc, off, 64);
  if (lane == 0) {
    float z;
    if (mode == 0) {
      z = BN_INV * g[o] * acc + bbn[o];
      z = z >= 0.f ? z : 0.2f * z;
    } else if (mode == 1) {
      z = BN_INV * g[o] * (acc + eb[o]) + bbn[o];
      z = z >= 0.f ? z : 0.2f * z;
    } else {
      z = acc + eb[o];
    }
    out[(size_t)b * O + o] = z;
  }
}

// ---------------------------------------------------------------- host
extern "C" void kernel_launch(void* const* d_in, const int* in_sizes, int n_in,
                              void* d_out, int out_size, void* d_ws,
                              size_t ws_size, hipStream_t stream) {
  (void)in_sizes; (void)n_in; (void)out_size; (void)ws_size;
  const float* pts = (const float*)d_in[0];
  const float* W1 = (const float*)d_in[1];
  const float* g1 = (const float*)d_in[2];
  const float* b1 = (const float*)d_in[3];
  const float* W2 = (const float*)d_in[4];
  const float* g2 = (const float*)d_in[5];
  const float* b2 = (const float*)d_in[6];
  const float* W3 = (const float*)d_in[7];
  const float* g3 = (const float*)d_in[8];
  const float* b3 = (const float*)d_in[9];
  const float* W4 = (const float*)d_in[10];
  const float* g4 = (const float*)d_in[11];
  const float* b4 = (const float*)d_in[12];
  const float* W5 = (const float*)d_in[13];
  const float* g5 = (const float*)d_in[14];
  const float* b5 = (const float*)d_in[15];
  const float* Wl1 = (const float*)d_in[16];
  const float* g6 = (const float*)d_in[17];
  const float* b6 = (const float*)d_in[18];
  const float* Wl2 = (const float*)d_in[19];
  const float* bl2 = (const float*)d_in[20];
  const float* g7 = (const float*)d_in[21];
  const float* b7 = (const float*)d_in[22];
  const float* Wl3 = (const float*)d_in[23];
  const float* bl3 = (const float*)d_in[24];

  char* ws = (char*)d_ws;
  float* x0 = (float*)(ws + 0);                  // 196608
  float* cat = (float*)(ws + 196608);            // 33554432
  float* sq = (float*)(ws + 33751040);           // 65536
  int* idx = (int*)(ws + 33816576);              // 1310720
  float* y = (float*)(ws + 35127296);            // 16777216
  float* v = (float*)(ws + 51904512);            // 16777216
  float* pm = (float*)(ws + 68681728);           // 524288
  float* ps = (float*)(ws + 69206016);           // 524288
  float* feat = (float*)(ws + 69730304);         // 65536
  float* fc1o = (float*)(ws + 69795840);         // 16384
  float* fc2o = (float*)(ws + 69812224);         // 8192
  float* cv = (float*)(ws + 69820416);           // 33554432 (16384*512*4)
  int* ci = (int*)(ws + 103374848);              // 33554432

  k_unscramble<<<dim3(64), 256, 0, stream>>>(pts, x0, sq);

  // ---- layer 1: C=3 O=64
  k_pds<3><<<dim3(16, 16, BB), 256, 0, stream>>>(x0, 3, sq, cv, ci);
  k_msel<<<dim3(BB * NN / 4), 256, 0, stream>>>(cv, ci, idx);
  k_yv<3, 64><<<dim3(256, 1), 256, 0, stream>>>(x0, 3, W1, g1, b1, y, v);
  k_agg<64, true><<<dim3(BB * NN / 4), 256, 0, stream>>>(y, v, idx, cat, 0, sq);

  // ---- layer 2: C=64 O=64
  k_pds<64><<<dim3(16, 16, BB), 256, 0, stream>>>(cat, 512, sq, cv, ci);
  k_msel<<<dim3(BB * NN / 4), 256, 0, stream>>>(cv, ci, idx);
  k_yv<64, 64><<<dim3(256, 1), 256, 0, stream>>>(cat, 512, W2, g2, b2, y, v);
  k_agg<64, true><<<dim3(BB * NN / 4), 256, 0, stream>>>(y, v, idx, cat, 64, sq);

  // ---- layer 3: C=64 O=128
  k_pds<64><<<dim3(16, 16, BB), 256, 0, stream>>>(cat + 64, 512, sq, cv, ci);
  k_msel<<<dim3(BB * NN / 4), 256, 0, stream>>>(cv, ci, idx);
  k_yv<64, 128><<<dim3(256, 2), 256, 0, stream>>>(cat + 64, 512, W3, g3, b3, y, v);
  k_agg<128, true><<<dim3(BB * NN / 2), 256, 0, stream>>>(y, v, idx, cat, 128, sq);

  // ---- layer 4: C=128 O=256
  k_pds<128><<<dim3(16, 16, BB), 256, 0, stream>>>(cat + 128, 512, sq, cv, ci);
  k_msel<<<dim3(BB * NN / 4), 256, 0, stream>>>(cv, ci, idx);
  k_yv<128, 256><<<dim3(256, 4), 256, 0, stream>>>(cat + 128, 512, W4, g4, b4, y, v);
  k_agg<256, false><<<dim3(BB * NN), 256, 0, stream>>>(y, v, idx, cat, 256, nullptr);

  // ---- h5 (bf16 MFMA, fused max/mean partials) + feat
  k_h5r<<<dim3(128, 8), 256, 0, stream>>>(cat, W5, g5, b5, pm, ps);
  k_red2<<<dim3(32), 256, 0, stream>>>(pm, ps, feat);

  // ---- FC head
  k_fc<<<dim3(1024), 256, 0, stream>>>(feat, Wl1, g6, b6, nullptr, fc1o, 2048, 512, 0);
  k_fc<<<dim3(512), 256, 0, stream>>>(fc1o, Wl2, g7, b7, bl2, fc2o, 512, 256, 1);
  k_fc<<<dim3(80), 256, 0, stream>>>(fc2o, Wl3, nullptr, nullptr, bl3, (float*)d_out, 256, 40, 2);
}

// Round 16
// 907.173 us; speedup vs baseline: 2.1563x; 1.9864x over previous
//
#include <hip/hip_runtime.h>
#include <math.h>

#define BB 8
#define NN 2048
#define KNN 20
#define BN_INV 0.9999950000374997f

typedef __bf16 bf16x8 __attribute__((ext_vector_type(8)));
typedef __bf16 bf16x4 __attribute__((ext_vector_type(4)));
typedef float f32x4 __attribute__((ext_vector_type(4)));

// ---------------------------------------------------------------- unscramble
__global__ __launch_bounds__(256)
void k_unscramble(const float* __restrict__ pts, float* __restrict__ x0,
                  float* __restrict__ sq) {
  int t = blockIdx.x * 256 + threadIdx.x;
  if (t >= BB * NN) return;
  int b = t >> 11, n = t & (NN - 1);
  const float* p = pts + (size_t)b * 3 * NN;
  float a0 = p[n], a1 = p[NN + n], a2 = p[2 * NN + n];
  float* o = x0 + (size_t)t * 3;
  o[0] = a0; o[1] = a1; o[2] = a2;
  sq[t] = a0 * a0 + a1 * a1 + a2 * a2;
}

// ---------------------------------------------------------------- pd gemm
// r12 structure: 128x128 tile, 8x8/thread, unroll-1 c-loop (VGPR~76).
// r16: REGULAR stores (not NT) — pd slab (134MB) drains through L3 so
// k_select's re-read is L3-served instead of HBM (r8 evidence).
template <int C>
__global__ __launch_bounds__(256)
void k_pd(const float* __restrict__ Xin, int RS, const float* __restrict__ sq,
          float* __restrict__ pd, int b0) {
  constexpr int CH = (C < 32) ? C : 32;
  constexpr int CHP = (CH == 3) ? 3 : 36;
  __shared__ __align__(16) float Xi[128 * CHP];
  __shared__ __align__(16) float Xj[128 * CHP];
  int b = b0 + blockIdx.z;
  int i0 = blockIdx.x * 128, j0 = blockIdx.y * 128;
  const float* Xb = Xin + (size_t)b * NN * RS;
  int tid = threadIdx.x;
  int ti = tid & 15, tj = tid >> 4;
  float acc[8][8] = {};
  for (int c0 = 0; c0 < C; c0 += CH) {
    __syncthreads();
    if constexpr (CH == 32) {
      for (int t = tid; t < 128 * 8; t += 256) {
        int r = t >> 3, c = (t & 7) * 4;
        *(float4*)&Xi[r * CHP + c] =
            *(const float4*)&Xb[(size_t)(i0 + r) * RS + c0 + c];
        *(float4*)&Xj[r * CHP + c] =
            *(const float4*)&Xb[(size_t)(j0 + r) * RS + c0 + c];
      }
    } else {
      for (int t = tid; t < 128 * CH; t += 256) {
        int r = t / CH, c = t % CH;
        Xi[r * CHP + c] = Xb[(size_t)(i0 + r) * RS + c0 + c];
        Xj[r * CHP + c] = Xb[(size_t)(j0 + r) * RS + c0 + c];
      }
    }
    __syncthreads();
    if constexpr (CH % 4 == 0) {
      #pragma unroll 1
      for (int c = 0; c < CH; c += 4) {
        float4 ap[8], wq[8];
        #pragma unroll
        for (int p = 0; p < 8; p++)
          ap[p] = *(const float4*)&Xi[(ti + 16 * p) * CHP + c];
        #pragma unroll
        for (int q = 0; q < 8; q++)
          wq[q] = *(const float4*)&Xj[((q >> 2) * 64 + tj * 4 + (q & 3)) * CHP + c];
        #pragma unroll
        for (int p = 0; p < 8; p++)
          #pragma unroll
          for (int q = 0; q < 8; q++)
            acc[p][q] += ap[p].x * wq[q].x + ap[p].y * wq[q].y +
                         ap[p].z * wq[q].z + ap[p].w * wq[q].w;
      }
    } else {
      #pragma unroll 1
      for (int c = 0; c < CH; ++c) {
        float a[8], w[8];
        #pragma unroll
        for (int p = 0; p < 8; p++) a[p] = Xi[(ti + 16 * p) * CHP + c];
        #pragma unroll
        for (int q = 0; q < 8; q++)
          w[q] = Xj[((q >> 2) * 64 + tj * 4 + (q & 3)) * CHP + c];
        #pragma unroll
        for (int p = 0; p < 8; p++)
          #pragma unroll
          for (int q = 0; q < 8; q++) acc[p][q] += a[p] * w[q];
      }
    }
  }
  const float* sqb = sq + (size_t)b * NN;
  float* pdb = pd + (size_t)blockIdx.z * NN * NN;
  #pragma unroll
  for (int qh = 0; qh < 2; qh++) {
    int j = j0 + qh * 64 + tj * 4;
    float4 sq4 = *(const float4*)&sqb[j];
    #pragma unroll
    for (int p = 0; p < 8; p++) {
      int i = i0 + ti + 16 * p;
      float4 o;
      o.x = 2.f * acc[p][qh * 4 + 0] - sq4.x;
      o.y = 2.f * acc[p][qh * 4 + 1] - sq4.y;
      o.z = 2.f * acc[p][qh * 4 + 2] - sq4.z;
      o.w = 2.f * acc[p][qh * 4 + 3] - sq4.w;
      *(float4*)&pdb[(size_t)i * NN + j] = o;
    }
  }
}

// ---------------------------------------------------------------- knn select
// one wave per row; row cached in 32 regs/lane; 20x bitmask argmax,
// lowest index wins ties. Regular loads (pd now L3-resident).
__global__ __launch_bounds__(256)
void k_select(const float* __restrict__ pd, int* __restrict__ idx, int b0,
              int rows) {
  int wave = threadIdx.x >> 6;
  int lane = threadIdx.x & 63;
  int r = blockIdx.x * 4 + wave;  // slab-local row
  if (r >= rows) return;
  const float* row = pd + (size_t)r * NN;
  float rv[32];
  #pragma unroll
  for (int m = 0; m < 32; m++) rv[m] = row[m * 64 + lane];
  unsigned removed = 0u;
  int* out = idx + ((size_t)b0 * NN + r) * KNN;
  for (int k = 0; k < KNN; k++) {
    float lv = -INFINITY;
    int lm = 0;
    #pragma unroll
    for (int m = 0; m < 32; m++) {
      float vv = ((removed >> m) & 1u) ? -INFINITY : rv[m];
      if (vv > lv) { lv = vv; lm = m; }
    }
    float bv = lv;
    int bj = lm * 64 + lane;
    #pragma unroll
    for (int off = 32; off; off >>= 1) {
      float ov = __shfl_xor(bv, off, 64);
      int oj = __shfl_xor(bj, off, 64);
      if (ov > bv || (ov == bv && oj < bj)) { bv = ov; bj = oj; }
    }
    if (lane == 0) out[k] = bj;
    if (lane == (bj & 63)) removed |= (1u << (bj >> 6));
  }
}

// ---------------------------------------------------------------- y/v gemm
// r16: unroll-1 c-loop (cuts VGPR from 188 -> raises occupancy; r12 lesson)
template <int C, int O>
__global__ __launch_bounds__(256)
void k_yv(const float* __restrict__ Xin, int RS, const float* __restrict__ W,
          const float* __restrict__ g, const float* __restrict__ bbn,
          float* __restrict__ y, float* __restrict__ v) {
  constexpr int CH = (C < 32) ? C : 32;
  constexpr int CHP = (CH == 3) ? 3 : 36;
  __shared__ __align__(16) float Xs[64 * CHP];
  __shared__ __align__(16) float Wa[64 * CHP];
  __shared__ __align__(16) float Wd[64 * CHP];
  int r0 = blockIdx.x * 64, o0 = blockIdx.y * 64;
  int ti = threadIdx.x & 15, tj = threadIdx.x >> 4;
  float ay[4][4] = {}, av[4][4] = {};
  for (int c0 = 0; c0 < C; c0 += CH) {
    if constexpr (CH == 32) {
      for (int t = threadIdx.x; t < 64 * 8; t += 256) {
        int r = t >> 3, c = (t & 7) * 4;
        *(float4*)&Xs[r * CHP + c] =
            *(const float4*)&Xin[(size_t)(r0 + r) * RS + c0 + c];
        const float* wr = W + (size_t)(o0 + r) * (2 * C) + c0 + c;
        float4 wa4 = *(const float4*)wr;
        float4 wb4 = *(const float4*)(wr + C);
        *(float4*)&Wa[r * CHP + c] = wa4;
        float4 wd4;
        wd4.x = wb4.x - wa4.x; wd4.y = wb4.y - wa4.y;
        wd4.z = wb4.z - wa4.z; wd4.w = wb4.w - wa4.w;
        *(float4*)&Wd[r * CHP + c] = wd4;
      }
    } else {
      for (int t = threadIdx.x; t < 64 * CH; t += 256) {
        int r = t / CH, c = t % CH;
        Xs[r * CHP + c] = Xin[(size_t)(r0 + r) * RS + c0 + c];
        const float* wr = W + (size_t)(o0 + r) * (2 * C) + c0 + c;
        float wa_ = wr[0];
        Wa[r * CHP + c] = wa_;
        Wd[r * CHP + c] = wr[C] - wa_;
      }
    }
    __syncthreads();
    if constexpr (CH % 4 == 0) {
      #pragma unroll 1
      for (int c = 0; c < CH; c += 4) {
        float4 ap[4], qa[4], qd[4];
        #pragma unroll
        for (int p = 0; p < 4; p++)
          ap[p] = *(const float4*)&Xs[(ti + 16 * p) * CHP + c];
        #pragma unroll
        for (int q = 0; q < 4; q++) {
          qa[q] = *(const float4*)&Wa[(tj * 4 + q) * CHP + c];
          qd[q] = *(const float4*)&Wd[(tj * 4 + q) * CHP + c];
        }
        #pragma unroll
        for (int p = 0; p < 4; p++)
          #pragma unroll
          for (int q = 0; q < 4; q++) {
            ay[p][q] += ap[p].x * qa[q].x + ap[p].y * qa[q].y +
                        ap[p].z * qa[q].z + ap[p].w * qa[q].w;
            av[p][q] += ap[p].x * qd[q].x + ap[p].y * qd[q].y +
                        ap[p].z * qd[q].z + ap[p].w * qd[q].w;
          }
      }
    } else {
      #pragma unroll 1
      for (int c = 0; c < CH; ++c) {
        float a[4];
        #pragma unroll
        for (int p = 0; p < 4; p++) a[p] = Xs[(ti + 16 * p) * CHP + c];
        #pragma unroll
        for (int q = 0; q < 4; q++) {
          float wa_ = Wa[(tj * 4 + q) * CHP + c];
          float wd_ = Wd[(tj * 4 + q) * CHP + c];
          #pragma unroll
          for (int p = 0; p < 4; p++) {
            ay[p][q] += a[p] * wa_;
            av[p][q] += a[p] * wd_;
          }
        }
      }
    }
    __syncthreads();
  }
  #pragma unroll
  for (int p = 0; p < 4; p++) {
    int row = r0 + ti + 16 * p;
    float oy[4], ov[4];
    #pragma unroll
    for (int q = 0; q < 4; q++) {
      int o = o0 + tj * 4 + q;
      float s = BN_INV * g[o];
      oy[q] = s * ay[p][q];
      ov[q] = s * av[p][q] + bbn[o];
    }
    *(float4*)&y[(size_t)row * O + o0 + tj * 4] = *(float4*)oy;
    *(float4*)&v[(size_t)row * O + o0 + tj * 4] = *(float4*)ov;
  }
}

// ---------------------------------------------------------------- aggregate
template <int O, bool DO_SQ>
__global__ __launch_bounds__(256)
void k_agg(const float* __restrict__ y, const float* __restrict__ v,
           const int* __restrict__ idx, float* __restrict__ cat_out, int coloff,
           float* __restrict__ sqo) {
  constexpr int RPB = 256 / O;
  int rl = threadIdx.x / O;
  int o = threadIdx.x % O;
  int row = blockIdx.x * RPB + rl;  // b*N+n
  int b = row >> 11;
  const int* ix = idx + (size_t)row * KNN;
  float vv = v[(size_t)row * O + o];
  const float* yb = y + (size_t)b * NN * O;
  float m = -INFINITY;
  #pragma unroll
  for (int k = 0; k < KNN; k++) {
    int j = ix[k];
    m = fmaxf(m, yb[(size_t)j * O + o] + vv);
  }
  float out = m >= 0.f ? m : 0.2f * m;
  cat_out[(size_t)row * 512 + coloff + o] = out;
  if constexpr (DO_SQ) {
    constexpr int WPR = O / 64;
    float p2 = out * out;
    #pragma unroll
    for (int off = 32; off; off >>= 1) p2 += __shfl_xor(p2, off, 64);
    __shared__ float part[4];
    int wv = threadIdx.x >> 6;
    if ((threadIdx.x & 63) == 0) part[wv] = p2;
    __syncthreads();
    if ((threadIdx.x % O) == 0) {
      int w0 = threadIdx.x >> 6;
      float s = 0.f;
      #pragma unroll
      for (int w = 0; w < WPR; ++w) s += part[w0 + w];
      sqo[row] = s;
    }
  }
}

// ---------------------------------------------------------------- h5 + reduce
__global__ __launch_bounds__(256)
void k_h5r(const float* __restrict__ A, const float* __restrict__ W5,
           const float* __restrict__ g, const float* __restrict__ bbn,
           float* __restrict__ pm, float* __restrict__ ps) {
  __shared__ __align__(16) __bf16 Al[128 * 64];
  __shared__ __align__(16) __bf16 Bl[128 * 64];
  __shared__ float smax[2][128];
  __shared__ float ssum[2][128];
  int m0 = blockIdx.x * 128, o0 = blockIdx.y * 128;
  int w = threadIdx.x >> 6, lane = threadIdx.x & 63;
  int wm = w >> 1, wn = w & 1;
  f32x4 acc[4][4];
  #pragma unroll
  for (int f = 0; f < 4; f++)
    #pragma unroll
    for (int j = 0; j < 4; j++) acc[f][j] = (f32x4){0.f, 0.f, 0.f, 0.f};

  int wr0 = w * 32;
  int c8 = lane & 15;
  for (int k0 = 0; k0 < 512; k0 += 64) {
    #pragma unroll
    for (int i = 0; i < 8; i++) {
      int row = wr0 + i * 4 + (lane >> 4);
      float4 a4 = *(const float4*)&A[(size_t)(m0 + row) * 512 + k0 + c8 * 4];
      float4 b4 = *(const float4*)&W5[(size_t)(o0 + row) * 512 + k0 + c8 * 4];
      int el = (c8 * 4) ^ ((row & 7) << 3);
      bf16x4 ah, bh;
      ah.x = (__bf16)a4.x; ah.y = (__bf16)a4.y; ah.z = (__bf16)a4.z; ah.w = (__bf16)a4.w;
      bh.x = (__bf16)b4.x; bh.y = (__bf16)b4.y; bh.z = (__bf16)b4.z; bh.w = (__bf16)b4.w;
      *(bf16x4*)&Al[row * 64 + el] = ah;
      *(bf16x4*)&Bl[row * 64 + el] = bh;
    }
    __syncthreads();
    #pragma unroll
    for (int kk = 0; kk < 2; kk++) {
      bf16x8 af[4], bfr[4];
      int cb = (lane >> 4) + kk * 4;
      #pragma unroll
      for (int f = 0; f < 4; f++) {
        int ra = wm * 64 + f * 16 + (lane & 15);
        af[f] = *(const bf16x8*)&Al[ra * 64 + ((cb ^ (ra & 7)) * 8)];
        int rb = wn * 64 + f * 16 + (lane & 15);
        bfr[f] = *(const bf16x8*)&Bl[rb * 64 + ((cb ^ (rb & 7)) * 8)];
      }
      #pragma unroll
      for (int f = 0; f < 4; f++)
        #pragma unroll
        for (int j = 0; j < 4; j++)
          acc[f][j] = __builtin_amdgcn_mfma_f32_16x16x32_bf16(af[f], bfr[j],
                                                              acc[f][j], 0, 0, 0);
    }
    __syncthreads();
  }
  #pragma unroll
  for (int j = 0; j < 4; j++) {
    int o = o0 + wn * 64 + j * 16 + (lane & 15);
    float s = BN_INV * g[o], bb = bbn[o];
    float mx = -INFINITY, sm = 0.f;
    #pragma unroll
    for (int f = 0; f < 4; f++)
      #pragma unroll
      for (int r = 0; r < 4; r++) {
        float z = s * acc[f][j][r] + bb;
        z = z >= 0.f ? z : 0.2f * z;
        mx = fmaxf(mx, z);
        sm += z;
      }
    mx = fmaxf(mx, __shfl_xor(mx, 16, 64)); sm += __shfl_xor(sm, 16, 64);
    mx = fmaxf(mx, __shfl_xor(mx, 32, 64)); sm += __shfl_xor(sm, 32, 64);
    if ((lane >> 4) == 0) {
      int cl = wn * 64 + j * 16 + (lane & 15);
      smax[wm][cl] = mx;
      ssum[wm][cl] = sm;
    }
  }
  __syncthreads();
  if (threadIdx.x < 128) {
    float m = fmaxf(smax[0][threadIdx.x], smax[1][threadIdx.x]);
    float sv = ssum[0][threadIdx.x] + ssum[1][threadIdx.x];
    pm[(size_t)blockIdx.x * 1024 + o0 + threadIdx.x] = m;
    ps[(size_t)blockIdx.x * 1024 + o0 + threadIdx.x] = sv;
  }
}

// ---------------------------------------------------------------- reductions
__global__ __launch_bounds__(256)
void k_red2(const float* __restrict__ pm, const float* __restrict__ ps,
            float* __restrict__ feat) {
  int gg = blockIdx.x * 256 + threadIdx.x;
  if (gg >= BB * 1024) return;
  int b = gg >> 10, o = gg & 1023;
  float m = -INFINITY, s = 0.f;
  for (int t = 0; t < 16; ++t) {
    m = fmaxf(m, pm[(size_t)(b * 16 + t) * 1024 + o]);
    s += ps[(size_t)(b * 16 + t) * 1024 + o];
  }
  feat[(size_t)b * 2048 + o] = m;
  feat[(size_t)b * 2048 + 1024 + o] = s * (1.f / 2048.f);
}

// ---------------------------------------------------------------- FC layers
__global__ __launch_bounds__(256)
void k_fc(const float* __restrict__ in, const float* __restrict__ W,
          const float* __restrict__ g, const float* __restrict__ bbn,
          const float* __restrict__ eb, float* __restrict__ out, int IN, int O,
          int mode) {
  int gid = (blockIdx.x * 256 + threadIdx.x) >> 6;
  int lane = threadIdx.x & 63;
  int b = gid / O, o = gid % O;
  if (b >= BB) return;
  const float* ip = in + (size_t)b * IN;
  const float* wp = W + (size_t)o * IN;
  float acc = 0.f;
  for (int i = lane; i < IN; i += 64) acc += ip[i] * wp[i];
  #pragma unroll
  for (int off = 32; off; off >>= 1) acc += __shfl_xor(acc, off, 64);
  if (lane == 0) {
    float z;
    if (mode == 0) {
      z = BN_INV * g[o] * acc + bbn[o];
      z = z >= 0.f ? z : 0.2f * z;
    } else if (mode == 1) {
      z = BN_INV * g[o] * (acc + eb[o]) + bbn[o];
      z = z >= 0.f ? z : 0.2f * z;
    } else {
      z = acc + eb[o];
    }
    out[(size_t)b * O + o] = z;
  }
}

// ---------------------------------------------------------------- host
extern "C" void kernel_launch(void* const* d_in, const int* in_sizes, int n_in,
                              void* d_out, int out_size, void* d_ws,
                              size_t ws_size, hipStream_t stream) {
  (void)in_sizes; (void)n_in; (void)out_size;
  const float* pts = (const float*)d_in[0];
  const float* W1 = (const float*)d_in[1];
  const float* g1 = (const float*)d_in[2];
  const float* b1 = (const float*)d_in[3];
  const float* W2 = (const float*)d_in[4];
  const float* g2 = (const float*)d_in[5];
  const float* b2 = (const float*)d_in[6];
  const float* W3 = (const float*)d_in[7];
  const float* g3 = (const float*)d_in[8];
  const float* b3 = (const float*)d_in[9];
  const float* W4 = (const float*)d_in[10];
  const float* g4 = (const float*)d_in[11];
  const float* b4 = (const float*)d_in[12];
  const float* W5 = (const float*)d_in[13];
  const float* g5 = (const float*)d_in[14];
  const float* b5 = (const float*)d_in[15];
  const float* Wl1 = (const float*)d_in[16];
  const float* g6 = (const float*)d_in[17];
  const float* b6 = (const float*)d_in[18];
  const float* Wl2 = (const float*)d_in[19];
  const float* bl2 = (const float*)d_in[20];
  const float* g7 = (const float*)d_in[21];
  const float* b7 = (const float*)d_in[22];
  const float* Wl3 = (const float*)d_in[23];
  const float* bl3 = (const float*)d_in[24];

  char* ws = (char*)d_ws;
  float* x0 = (float*)(ws + 0);                  // 196608
  float* cat = (float*)(ws + 196608);            // 33554432
  float* sq = (float*)(ws + 33751040);           // 65536
  int* idx = (int*)(ws + 33816576);              // 1310720
  float* y = (float*)(ws + 35127296);            // 16777216
  float* v = (float*)(ws + 51904512);            // 16777216
  float* pm = (float*)(ws + 68681728);           // 524288
  float* ps = (float*)(ws + 69206016);           // 524288
  float* feat = (float*)(ws + 69730304);         // 65536
  float* fc1o = (float*)(ws + 69795840);         // 16384
  float* fc2o = (float*)(ws + 69812224);         // 8192
  float* big = (float*)(ws + 69820416);          // pd slab

  size_t avail = ws_size > (size_t)69820416 ? ws_size - (size_t)69820416 : 0;
  int slabB = (int)(avail / ((size_t)NN * NN * 4));
  if (slabB > BB) slabB = BB;
  if (slabB < 1) slabB = 1;

  k_unscramble<<<dim3(64), 256, 0, stream>>>(pts, x0, sq);

  // ---- layer 1: C=3 O=64
  for (int b0 = 0; b0 < BB; b0 += slabB) {
    int sb = BB - b0 < slabB ? BB - b0 : slabB;
    k_pd<3><<<dim3(16, 16, sb), 256, 0, stream>>>(x0, 3, sq, big, b0);
    k_select<<<dim3(sb * NN / 4), 256, 0, stream>>>(big, idx, b0, sb * NN);
  }
  k_yv<3, 64><<<dim3(256, 1), 256, 0, stream>>>(x0, 3, W1, g1, b1, y, v);
  k_agg<64, true><<<dim3(BB * NN / 4), 256, 0, stream>>>(y, v, idx, cat, 0, sq);

  // ---- layer 2: C=64 O=64
  for (int b0 = 0; b0 < BB; b0 += slabB) {
    int sb = BB - b0 < slabB ? BB - b0 : slabB;
    k_pd<64><<<dim3(16, 16, sb), 256, 0, stream>>>(cat, 512, sq, big, b0);
    k_select<<<dim3(sb * NN / 4), 256, 0, stream>>>(big, idx, b0, sb * NN);
  }
  k_yv<64, 64><<<dim3(256, 1), 256, 0, stream>>>(cat, 512, W2, g2, b2, y, v);
  k_agg<64, true><<<dim3(BB * NN / 4), 256, 0, stream>>>(y, v, idx, cat, 64, sq);

  // ---- layer 3: C=64 O=128
  for (int b0 = 0; b0 < BB; b0 += slabB) {
    int sb = BB - b0 < slabB ? BB - b0 : slabB;
    k_pd<64><<<dim3(16, 16, sb), 256, 0, stream>>>(cat + 64, 512, sq, big, b0);
    k_select<<<dim3(sb * NN / 4), 256, 0, stream>>>(big, idx, b0, sb * NN);
  }
  k_yv<64, 128><<<dim3(256, 2), 256, 0, stream>>>(cat + 64, 512, W3, g3, b3, y, v);
  k_agg<128, true><<<dim3(BB * NN / 2), 256, 0, stream>>>(y, v, idx, cat, 128, sq);

  // ---- layer 4: C=128 O=256
  for (int b0 = 0; b0 < BB; b0 += slabB) {
    int sb = BB - b0 < slabB ? BB - b0 : slabB;
    k_pd<128><<<dim3(16, 16, sb), 256, 0, stream>>>(cat + 128, 512, sq, big, b0);
    k_select<<<dim3(sb * NN / 4), 256, 0, stream>>>(big, idx, b0, sb * NN);
  }
  k_yv<128, 256><<<dim3(256, 4), 256, 0, stream>>>(cat + 128, 512, W4, g4, b4, y, v);
  k_agg<256, false><<<dim3(BB * NN), 256, 0, stream>>>(y, v, idx, cat, 256, nullptr);

  // ---- h5 (bf16 MFMA, fused max/mean partials) + feat
  k_h5r<<<dim3(128, 8), 256, 0, stream>>>(cat, W5, g5, b5, pm, ps);
  k_red2<<<dim3(32), 256, 0, stream>>>(pm, ps, feat);

  // ---- FC head
  k_fc<<<dim3(1024), 256, 0, stream>>>(feat, Wl1, g6, b6, nullptr, fc1o, 2048, 512, 0);
  k_fc<<<dim3(512), 256, 0, stream>>>(fc1o, Wl2, g7, b7, bl2, fc2o, 512, 256, 1);
  k_fc<<<dim3(80), 256, 0, stream>>>(fc2o, Wl3, nullptr, nullptr, bl3, (float*)d_out, 256, 40, 2);
}